// Round 1
// baseline (2404.196 us; speedup 1.0000x reference)
//
#include <hip/hip_runtime.h>
#include <cstdint>
#include <cstddef>

// ---------------------------------------------------------------------------
// GPT forward, MI355X/gfx950. bf16 MFMA GEMMs (16x16x32), f32 accumulate.
// Fragment layouts (learn_hip m89/m91 verified):
//   A-frag: A[m = lane&15][k = (lane>>4)*8 + j]   (8 bf16, 16B contiguous)
//   B-frag: B[k = (lane>>4)*8 + j][n = lane&15]
//   C/D   : row = (lane>>4)*4 + reg, col = lane&15
// This revision: GEMM staging via global_load_lds width-16 (linear LDS dest,
// inverse-swizzled per-lane SOURCE, swizzled read — guide rule #21), plus a
// 128x128-tile m97-structure kernel for fc (N=4096) and lm_head (N=32000).
// ---------------------------------------------------------------------------

typedef __attribute__((ext_vector_type(8))) short short8;
typedef __attribute__((ext_vector_type(4))) float floatx4;

#define LOG2E 1.44269504088896340736f

static __device__ __forceinline__ unsigned short f2bf(float f) {
    unsigned int u = __float_as_uint(f);
    u += 0x7fffu + ((u >> 16) & 1u);   // RNE; inputs are finite
    return (unsigned short)(u >> 16);
}
static __device__ __forceinline__ float bf2f(unsigned short h) {
    return __uint_as_float(((unsigned int)h) << 16);
}

// global (16B per lane) -> LDS direct, wave-uniform LDS base + lane*16
static __device__ __forceinline__ void gload16(const uint4* g, const unsigned short* l) {
    __builtin_amdgcn_global_load_lds(
        (const __attribute__((address_space(1))) unsigned int*)g,
        (__attribute__((address_space(3))) unsigned int*)l,
        16, 0, 0);
}

// ---------------------------------------------------------------------------
// Embedding: x[s] = wte[tok[s]] + bigram_scale * bigram[hash(s)]
// ---------------------------------------------------------------------------
__global__ __launch_bounds__(256) void embed_kernel(
    const int* __restrict__ tok, const float* __restrict__ wte,
    const float* __restrict__ big, const float* __restrict__ bscale,
    float* __restrict__ X)
{
    int s = blockIdx.x, tid = threadIdx.x;
    int t = tok[s];
    int idx;
    if (s == 0) {
        idx = 65535;
    } else {
        // int32 wraparound products (values < 2^31 here), python-style mod
        int h = (int)(36313u * (unsigned)t) ^ (int)(27191u * (unsigned)tok[s - 1]);
        int r = h % 65535;
        if (r < 0) r += 65535;
        idx = r;
    }
    float sc = bscale[0];
    float4 w = *(const float4*)(wte + (size_t)t * 1024 + tid * 4);
    float4 b = *(const float4*)(big + (size_t)idx * 1024 + tid * 4);
    float4 o;
    o.x = w.x + sc * b.x; o.y = w.y + sc * b.y;
    o.z = w.z + sc * b.z; o.w = w.w + sc * b.w;
    *(float4*)(X + (size_t)s * 1024 + tid * 4) = o;
}

// ---------------------------------------------------------------------------
// Row RMSNorm (1024 f32) -> bf16
// ---------------------------------------------------------------------------
__global__ __launch_bounds__(256) void rmsnorm_kernel(
    const float* __restrict__ X, unsigned short* __restrict__ O)
{
    int s = blockIdx.x, tid = threadIdx.x;
    __shared__ float red[4];
    float4 v = *(const float4*)(X + (size_t)s * 1024 + tid * 4);
    float ss = v.x * v.x + v.y * v.y + v.z * v.z + v.w * v.w;
#pragma unroll
    for (int off = 32; off >= 1; off >>= 1) ss += __shfl_xor(ss, off, 64);
    if ((tid & 63) == 0) red[tid >> 6] = ss;
    __syncthreads();
    float tot = red[0] + red[1] + red[2] + red[3];
    float inv = rsqrtf(tot * (1.f / 1024.f) + 1e-6f);
    ushort4 o;
    o.x = f2bf(v.x * inv); o.y = f2bf(v.y * inv);
    o.z = f2bf(v.z * inv); o.w = f2bf(v.w * inv);
    *(ushort4*)(O + (size_t)s * 1024 + tid * 4) = o;
}

// ---------------------------------------------------------------------------
// Weight transpose+convert: W f32 [Z][K][N] -> Wt bf16 [Z][N][K]
// out row stride = K; out z-stride = out_z (lets Wq/Wk/Wv pack into [1536][1024])
// ---------------------------------------------------------------------------
__global__ __launch_bounds__(256) void wtrans_kernel(
    const float* __restrict__ W, unsigned short* __restrict__ Wt,
    int K, int N, unsigned long long out_z)
{
    int z = blockIdx.z;
    const float* Wz = W + (size_t)z * (size_t)K * N;
    unsigned short* Wtz = Wt + (size_t)z * out_z;
    int n0 = blockIdx.x * 64, k0 = blockIdx.y * 64;
    __shared__ unsigned int T[64 * 33];  // [k][n-pair], stride 33 words (conflict-free)
    int tid = threadIdx.x;
#pragma unroll
    for (int p = 0; p < 4; p++) {
        int idx = p * 256 + tid;
        int r = idx >> 4, c4 = idx & 15;
        float4 v = *(const float4*)(Wz + (size_t)(k0 + r) * N + n0 + c4 * 4);
        T[r * 33 + c4 * 2]     = (unsigned)f2bf(v.x) | ((unsigned)f2bf(v.y) << 16);
        T[r * 33 + c4 * 2 + 1] = (unsigned)f2bf(v.z) | ((unsigned)f2bf(v.w) << 16);
    }
    __syncthreads();
#pragma unroll
    for (int p = 0; p < 2; p++) {
        int idx = p * 256 + tid;
        int n = idx >> 3, c8 = idx & 7;
        unsigned h[8];
#pragma unroll
        for (int j = 0; j < 8; j++) {
            unsigned wv = T[(c8 * 8 + j) * 33 + (n >> 1)];
            h[j] = (n & 1) ? (wv >> 16) : (wv & 0xffffu);
        }
        uint4 val;
        val.x = h[0] | (h[1] << 16);
        val.y = h[2] | (h[3] << 16);
        val.z = h[4] | (h[5] << 16);
        val.w = h[6] | (h[7] << 16);
        *(uint4*)(Wtz + (size_t)(n0 + n) * K + k0 + c8 * 8) = val;
    }
}

// ---------------------------------------------------------------------------
// GEMM 64x64 tile: C[M,N] = A_bf16[M,K] @ Bt_bf16[N,K]^T
// BK=64, 4 waves (2x2) of 32x32. Staging: global_load_lds width-16, linear
// LDS dest, source chunk pre-swizzled (csrc = (lane&7)^(lane>>3)), reads use
// the matching XOR swizzle.
// MODE 0: outF = acc
// MODE 1: outF = resid + acc
// MODE 2: outH = bf16( leaky_relu(acc,0.5)^2 )
// ---------------------------------------------------------------------------
template <int MODE>
__global__ __launch_bounds__(256) void gemm_kernel(
    const unsigned short* __restrict__ A, const unsigned short* __restrict__ Bt,
    const float* __restrict__ resid, float* __restrict__ outF,
    unsigned short* __restrict__ outH, int M, int N, int K)
{
    __shared__ unsigned short As[64 * 64];
    __shared__ unsigned short Bs[64 * 64];
    int tid = threadIdx.x;
    int n0 = blockIdx.x * 64, m0 = blockIdx.y * 64;
    int wid = tid >> 6, lane = tid & 63;
    int l15 = lane & 15, quad = lane >> 4;
    int wm = (wid >> 1) * 32, wn = (wid & 1) * 32;
    int sw = l15 & 7;

    floatx4 acc[2][2] = {};

    const int Kv = K >> 3;
    const uint4* Ag = (const uint4*)A;
    const uint4* Bg = (const uint4*)Bt;

    int lr = lane >> 3;          // 0..7 : row within 8-row group
    int csrc = (lane & 7) ^ lr;  // inverse-swizzled source chunk

    for (int k0 = 0; k0 < K; k0 += 64) {
        int kc = k0 >> 3;
#pragma unroll
        for (int p = 0; p < 2; p++) {
            int r = p * 32 + wid * 8 + lr;
            gload16(Ag + (size_t)(m0 + r) * Kv + kc + csrc, &As[p * 2048 + wid * 512]);
            gload16(Bg + (size_t)(n0 + r) * Kv + kc + csrc, &Bs[p * 2048 + wid * 512]);
        }
        __syncthreads();
#pragma unroll
        for (int kk = 0; kk < 64; kk += 32) {
            int cb = (kk >> 3) + quad;
            int co = (cb ^ sw) << 3;
            short8 a0 = *(const short8*)&As[(wm + l15) * 64 + co];
            short8 a1 = *(const short8*)&As[(wm + 16 + l15) * 64 + co];
            short8 b0 = *(const short8*)&Bs[(wn + l15) * 64 + co];
            short8 b1 = *(const short8*)&Bs[(wn + 16 + l15) * 64 + co];
            acc[0][0] = __builtin_amdgcn_mfma_f32_16x16x32_bf16(a0, b0, acc[0][0], 0, 0, 0);
            acc[0][1] = __builtin_amdgcn_mfma_f32_16x16x32_bf16(a0, b1, acc[0][1], 0, 0, 0);
            acc[1][0] = __builtin_amdgcn_mfma_f32_16x16x32_bf16(a1, b0, acc[1][0], 0, 0, 0);
            acc[1][1] = __builtin_amdgcn_mfma_f32_16x16x32_bf16(a1, b1, acc[1][1], 0, 0, 0);
        }
        __syncthreads();
    }

#pragma unroll
    for (int mi = 0; mi < 2; mi++) {
#pragma unroll
        for (int ni = 0; ni < 2; ni++) {
#pragma unroll
            for (int r = 0; r < 4; r++) {
                int row = m0 + wm + mi * 16 + quad * 4 + r;
                int col = n0 + wn + ni * 16 + l15;
                size_t off = (size_t)row * N + col;
                float v = acc[mi][ni][r];
                if (MODE == 0) {
                    outF[off] = v;
                } else if (MODE == 1) {
                    outF[off] = resid[off] + v;
                } else {
                    float t = v >= 0.f ? v : 0.5f * v;
                    outH[off] = f2bf(t * t);
                }
            }
        }
    }
}

// ---------------------------------------------------------------------------
// GEMM 128x128 tile (m97 structure): 4 waves (2x2) of 64x64, BK=64,
// global_load_lds staging, XOR-swizzled reads. For fc and lm_head.
// ---------------------------------------------------------------------------
template <int MODE>
__global__ __launch_bounds__(256) void gemm128_kernel(
    const unsigned short* __restrict__ A, const unsigned short* __restrict__ Bt,
    const float* __restrict__ resid, float* __restrict__ outF,
    unsigned short* __restrict__ outH, int M, int N, int K)
{
    __shared__ unsigned short As[128 * 64];
    __shared__ unsigned short Bs[128 * 64];
    int tid = threadIdx.x;
    int n0 = blockIdx.x * 128, m0 = blockIdx.y * 128;
    int wid = tid >> 6, lane = tid & 63;
    int l15 = lane & 15, quad = lane >> 4;
    int wm = (wid >> 1) * 64, wn = (wid & 1) * 64;
    int sw = l15 & 7;

    floatx4 acc[4][4] = {};

    const int Kv = K >> 3;
    const uint4* Ag = (const uint4*)A;
    const uint4* Bg = (const uint4*)Bt;

    int lr = lane >> 3;          // 0..7
    int csrc = (lane & 7) ^ lr;  // inverse-swizzled source chunk

    for (int k0 = 0; k0 < K; k0 += 64) {
        int kc = k0 >> 3;
#pragma unroll
        for (int p = 0; p < 4; p++) {
            int r = p * 32 + wid * 8 + lr;
            gload16(Ag + (size_t)(m0 + r) * Kv + kc + csrc, &As[p * 2048 + wid * 512]);
            gload16(Bg + (size_t)(n0 + r) * Kv + kc + csrc, &Bs[p * 2048 + wid * 512]);
        }
        __syncthreads();
#pragma unroll
        for (int kk = 0; kk < 64; kk += 32) {
            int cb = (kk >> 3) + quad;
            int co = (cb ^ sw) << 3;
            short8 a[4], b[4];
#pragma unroll
            for (int i = 0; i < 4; i++) {
                a[i] = *(const short8*)&As[(wm + i * 16 + l15) * 64 + co];
                b[i] = *(const short8*)&Bs[(wn + i * 16 + l15) * 64 + co];
            }
#pragma unroll
            for (int mi = 0; mi < 4; mi++)
#pragma unroll
                for (int ni = 0; ni < 4; ni++)
                    acc[mi][ni] = __builtin_amdgcn_mfma_f32_16x16x32_bf16(a[mi], b[ni], acc[mi][ni], 0, 0, 0);
        }
        __syncthreads();
    }

#pragma unroll
    for (int mi = 0; mi < 4; mi++) {
#pragma unroll
        for (int ni = 0; ni < 4; ni++) {
#pragma unroll
            for (int r = 0; r < 4; r++) {
                int row = m0 + wm + mi * 16 + quad * 4 + r;
                int col = n0 + wn + ni * 16 + l15;
                size_t off = (size_t)row * N + col;
                float v = acc[mi][ni][r];
                if (MODE == 0) {
                    outF[off] = v;
                } else if (MODE == 1) {
                    outF[off] = resid[off] + v;
                } else {
                    float t = v >= 0.f ? v : 0.5f * v;
                    outH[off] = f2bf(t * t);
                }
            }
        }
    }
}

// ---------------------------------------------------------------------------
// Gate: gate[s][h] = sigmoid(xn[s] . gate_w[:,h] + gate_b[h])
// ---------------------------------------------------------------------------
__global__ __launch_bounds__(256) void gate_kernel(
    const unsigned short* __restrict__ Xn, const float* __restrict__ Gw,
    const float* __restrict__ Gb, float* __restrict__ Gate)
{
    int s = blockIdx.x, tid = threadIdx.x;
    __shared__ float xr[1024];
    {
        ushort4 u = *(const ushort4*)(Xn + (size_t)s * 1024 + tid * 4);
        xr[tid * 4 + 0] = bf2f(u.x); xr[tid * 4 + 1] = bf2f(u.y);
        xr[tid * 4 + 2] = bf2f(u.z); xr[tid * 4 + 3] = bf2f(u.w);
    }
    __syncthreads();
    int head = tid >> 4, l16 = tid & 15;
    float acc = 0.f;
#pragma unroll 8
    for (int j = 0; j < 64; j++) {
        int k = l16 + 16 * j;
        acc += xr[k] * Gw[k * 16 + head];
    }
#pragma unroll
    for (int off = 8; off >= 1; off >>= 1) acc += __shfl_xor(acc, off, 16);
    if (l16 == 0) Gate[s * 16 + head] = 1.f / (1.f + expf(-(acc + Gb[head])));
}

// ---------------------------------------------------------------------------
// Per-(s,head) RMSNorm + RoPE for q,k. q gets (q_gain*0.125) folded in.
// Outputs head-major bf16: Qb [16][S][64], Kb [4][S][64].
// ---------------------------------------------------------------------------
static __device__ __forceinline__ void norm_rope_store(
    const float* __restrict__ src, unsigned short* __restrict__ dst,
    int l16, float pos, float extragain)
{
    float4 xv = *(const float4*)(src + l16 * 4);
    float ss = xv.x * xv.x + xv.y * xv.y + xv.z * xv.z + xv.w * xv.w;
#pragma unroll
    for (int off = 8; off >= 1; off >>= 1) ss += __shfl_xor(ss, off, 16);
    float inv = rsqrtf(ss * (1.f / 64.f) + 1e-6f);
    float gain = extragain * inv;
    float a[4] = {xv.x, xv.y, xv.z, xv.w};
    float b[4];
#pragma unroll
    for (int e = 0; e < 4; e++) b[e] = __shfl_xor(a[e], 8, 16);  // partner: d ^ 32
    int d0 = l16 * 4;
    unsigned short o[4];
#pragma unroll
    for (int e = 0; e < 4; e++) {
        int d = d0 + e;
        int j = d & 31;
        float fr = pos * exp2f(-(float)j * (13.287712379549449f / 32.f));  // log2(10000)
        float c = cosf(fr), sn = sinf(fr);
        float val = (d < 32) ? (a[e] * c + b[e] * sn) : (a[e] * c - b[e] * sn);
        o[e] = f2bf(val * gain);
    }
    ushort4 ov; ov.x = o[0]; ov.y = o[1]; ov.z = o[2]; ov.w = o[3];
    *(ushort4*)(dst + d0) = ov;
}

__global__ __launch_bounds__(256) void qkrope_kernel(
    const float* __restrict__ QKV,   // [S][1536] (q | k | v)
    const float* __restrict__ qgain, // [16] this layer
    unsigned short* __restrict__ Qb, unsigned short* __restrict__ Kb)
{
    int s = blockIdx.x, tid = threadIdx.x;
    int g = tid >> 4, l16 = tid & 15;
    float pos = (float)s;
    norm_rope_store(QKV + (size_t)s * 1536 + g * 64, Qb + ((size_t)g * 1024 + s) * 64,
                    l16, pos, qgain[g] * 0.125f);
    if (g < 4) {
        norm_rope_store(QKV + (size_t)s * 1536 + 1024 + g * 64,
                        Kb + ((size_t)g * 1024 + s) * 64, l16, pos, 1.f);
    }
}

// ---------------------------------------------------------------------------
// Value residual mix + transpose: Vt[hkv][64][S] bf16 (dim-major for PV B-frags)
// layer 0: store raw v to V0, mix = lam1*v; else mix = lam0*v0 + lam1*v
// ---------------------------------------------------------------------------
__global__ __launch_bounds__(256) void vmix_kernel(
    const float* __restrict__ QKV, float* __restrict__ V0,
    unsigned short* __restrict__ Vt, const float* __restrict__ vrl, int isL0)
{
    int g = blockIdx.x;    // kv head
    int st = blockIdx.y;   // s-tile of 64
    float lam0 = vrl[0], lam1 = vrl[1];
    __shared__ unsigned short T[64 * 72];
    int tid = threadIdx.x;
#pragma unroll
    for (int p = 0; p < 4; p++) {
        int idx = p * 256 + tid;
        int r = idx >> 4, c4 = idx & 15;
        int srow = st * 64 + r;
        int coff = g * 64 + c4 * 4;
        float4 vv = *(const float4*)(QKV + (size_t)srow * 1536 + 1280 + coff);
        float4 m;
        if (isL0) {
            *(float4*)(V0 + (size_t)srow * 256 + coff) = vv;
            m.x = lam1 * vv.x; m.y = lam1 * vv.y; m.z = lam1 * vv.z; m.w = lam1 * vv.w;
        } else {
            float4 v0v = *(const float4*)(V0 + (size_t)srow * 256 + coff);
            m.x = lam0 * v0v.x + lam1 * vv.x; m.y = lam0 * v0v.y + lam1 * vv.y;
            m.z = lam0 * v0v.z + lam1 * vv.z; m.w = lam0 * v0v.w + lam1 * vv.w;
        }
        T[(c4 * 4 + 0) * 72 + r] = f2bf(m.x);
        T[(c4 * 4 + 1) * 72 + r] = f2bf(m.y);
        T[(c4 * 4 + 2) * 72 + r] = f2bf(m.z);
        T[(c4 * 4 + 3) * 72 + r] = f2bf(m.w);
    }
    __syncthreads();
#pragma unroll
    for (int p = 0; p < 2; p++) {
        int idx = p * 256 + tid;
        int d = idx >> 3, s8 = idx & 7;
        uint4 val = *(const uint4*)&T[d * 72 + s8 * 8];
        *(uint4*)(Vt + ((size_t)g * 64 + d) * 1024 + st * 64 + s8 * 8) = val;
    }
}

// ---------------------------------------------------------------------------
// Flash attention: 1 wave per (head, 16-query tile). Causal, GQA group=4.
// Scale+q_gain already folded into Qb. Epilogue multiplies by sigmoid gate,
// writes y bf16 [S][1024].
// ---------------------------------------------------------------------------
__global__ __launch_bounds__(64) void attn_kernel(
    const unsigned short* __restrict__ Qb, const unsigned short* __restrict__ Kb,
    const unsigned short* __restrict__ Vt, const float* __restrict__ Gate,
    unsigned short* __restrict__ Y)
{
    const int S = 1024;
    int wid = blockIdx.x;
    int head = wid >> 6;
    int q0 = (wid & 63) << 4;
    int hkv = head >> 2;
    int lane = threadIdx.x;
    int l15 = lane & 15, quad = lane >> 4;

    __shared__ unsigned short Pl[16 * 40];  // P tile, C-layout -> A-layout round trip

    const unsigned short* Qp = Qb + ((size_t)(head * S + q0 + l15)) * 64 + quad * 8;
    short8 qf0 = *(const short8*)(Qp);
    short8 qf1 = *(const short8*)(Qp + 32);

    floatx4 oacc[4] = {};
    float m_r[4], l_r[4];
#pragma unroll
    for (int r = 0; r < 4; r++) { m_r[r] = -1e30f; l_r[r] = 0.f; }

    int nkb = (q0 >> 5) + 1;
    const unsigned short* Kbase = Kb + (size_t)hkv * S * 64;
    const unsigned short* Vbase = Vt + (size_t)hkv * 64 * S;

    for (int kb = 0; kb < nkb; kb++) {
        int kk = kb << 5;
        const unsigned short* Kp = Kbase + (size_t)(kk + l15) * 64 + quad * 8;
        short8 k00 = *(const short8*)(Kp);
        short8 k01 = *(const short8*)(Kp + 32);
        short8 k10 = *(const short8*)(Kp + 16 * 64);
        short8 k11 = *(const short8*)(Kp + 16 * 64 + 32);
        floatx4 s0 = {0.f, 0.f, 0.f, 0.f}, s1 = {0.f, 0.f, 0.f, 0.f};
        s0 = __builtin_amdgcn_mfma_f32_16x16x32_bf16(qf0, k00, s0, 0, 0, 0);
        s0 = __builtin_amdgcn_mfma_f32_16x16x32_bf16(qf1, k01, s0, 0, 0, 0);
        s1 = __builtin_amdgcn_mfma_f32_16x16x32_bf16(qf0, k10, s1, 0, 0, 0);
        s1 = __builtin_amdgcn_mfma_f32_16x16x32_bf16(qf1, k11, s1, 0, 0, 0);

#pragma unroll
        for (int r = 0; r < 4; r++) {
            int row = q0 + (quad << 2) + r;
            float v0s = (kk + l15 <= row) ? s0[r] : -1e30f;
            float v1s = (kk + 16 + l15 <= row) ? s1[r] : -1e30f;
            float mx = fmaxf(v0s, v1s);
#pragma unroll
            for (int off = 8; off >= 1; off >>= 1) mx = fmaxf(mx, __shfl_xor(mx, off, 16));
            float mnew = fmaxf(m_r[r], mx);
            float alpha = exp2f((m_r[r] - mnew) * LOG2E);
            float p0 = exp2f((v0s - mnew) * LOG2E);
            float p1 = exp2f((v1s - mnew) * LOG2E);
            float sum = p0 + p1;
#pragma unroll
            for (int off = 8; off >= 1; off >>= 1) sum += __shfl_xor(sum, off, 16);
            l_r[r] = l_r[r] * alpha + sum;
            m_r[r] = mnew;
#pragma unroll
            for (int ni = 0; ni < 4; ni++) oacc[ni][r] *= alpha;
            int prow = (quad << 2) + r;
            Pl[prow * 40 + l15] = f2bf(p0);
            Pl[prow * 40 + 16 + l15] = f2bf(p1);
        }
        short8 pf = *(const short8*)&Pl[l15 * 40 + quad * 8];
#pragma unroll
        for (int ni = 0; ni < 4; ni++) {
            short8 vf = *(const short8*)(Vbase + (size_t)(ni * 16 + l15) * S + kk + quad * 8);
            oacc[ni] = __builtin_amdgcn_mfma_f32_16x16x32_bf16(pf, vf, oacc[ni], 0, 0, 0);
        }
    }

#pragma unroll
    for (int ni = 0; ni < 4; ni++) {
#pragma unroll
        for (int r = 0; r < 4; r++) {
            int row = q0 + (quad << 2) + r;
            float g = Gate[row * 16 + head];
            float ov = oacc[ni][r] * (1.f / l_r[r]) * g;
            Y[(size_t)row * 1024 + head * 64 + ni * 16 + l15] = f2bf(ov);
        }
    }
}

// ---------------------------------------------------------------------------
// Host
// ---------------------------------------------------------------------------
template <int MODE>
static void launch_gemm(hipStream_t stream, const unsigned short* A,
                        const unsigned short* Bt, const float* resid,
                        float* oF, unsigned short* oH, int M, int N, int K)
{
    dim3 g(N / 64, M / 64);
    gemm_kernel<MODE><<<g, 256, 0, stream>>>(A, Bt, resid, oF, oH, M, N, K);
}

template <int MODE>
static void launch_gemm128(hipStream_t stream, const unsigned short* A,
                           const unsigned short* Bt, const float* resid,
                           float* oF, unsigned short* oH, int M, int N, int K)
{
    dim3 g(N / 128, M / 128);
    gemm128_kernel<MODE><<<g, 256, 0, stream>>>(A, Bt, resid, oF, oH, M, N, K);
}

extern "C" void kernel_launch(void* const* d_in, const int* in_sizes, int n_in,
                              void* d_out, int out_size, void* d_ws, size_t ws_size,
                              hipStream_t stream)
{
    (void)in_sizes; (void)n_in; (void)out_size;
    const int*   tok   = (const int*)d_in[0];
    const float* wte   = (const float*)d_in[1];
    const float* bigE  = (const float*)d_in[2];
    const float* bscal = (const float*)d_in[3];
    const float* Wq    = (const float*)d_in[4];
    const float* Wk    = (const float*)d_in[5];
    const float* Wv    = (const float*)d_in[6];
    const float* Wo    = (const float*)d_in[7];
    const float* qgain = (const float*)d_in[8];
    const float* vrl   = (const float*)d_in[9];
    const float* gw    = (const float*)d_in[10];
    const float* gb    = (const float*)d_in[11];
    const float* fcw   = (const float*)d_in[12];
    const float* prw   = (const float*)d_in[13];
    const float* lmw   = (const float*)d_in[14];
    float* out = (float*)d_out;

    char* ws = (char*)d_ws;
    size_t off = 0;
    auto alloc = [&](size_t bytes) -> void* {
        void* p = ws + off;
        off += (bytes + 255) & ~(size_t)255;
        return p;
    };

    float*          x    = (float*)alloc((size_t)1048576 * 4);
    float*          x2   = (float*)alloc((size_t)1048576 * 4);
    unsigned short* xn   = (unsigned short*)alloc((size_t)1048576 * 2);
    float*          qkv  = (float*)alloc((size_t)1572864 * 4);
    float*          v0   = (float*)alloc((size_t)262144 * 4);
    unsigned short* qb   = (unsigned short*)alloc((size_t)1048576 * 2);
    unsigned short* kbuf = (unsigned short*)alloc((size_t)262144 * 2);
    unsigned short* vt   = (unsigned short*)alloc((size_t)262144 * 2);
    float*          gbuf = (float*)alloc((size_t)16384 * 4);
    unsigned short* ybuf = (unsigned short*)alloc((size_t)1048576 * 2);
    unsigned short* hb   = (unsigned short*)alloc((size_t)4194304 * 2);

    const size_t qkvT_n = (size_t)8 * 1536 * 1024;
    const size_t woT_n  = (size_t)8 * 1024 * 1024;
    const size_t fcT_n  = (size_t)8 * 4096 * 1024;
    const size_t projT_n = (size_t)8 * 1024 * 4096;
    const size_t lmT_n  = (size_t)32000 * 1024;
    size_t bigNeed = off + 2 * (qkvT_n + woT_n + fcT_n + projT_n + lmT_n);
    bool bigPath = (ws_size >= bigNeed);

    auto wtr = [&](const float* W, unsigned short* Wt, int K, int N, int Z, size_t outz) {
        dim3 g(N / 64, K / 64, Z);
        wtrans_kernel<<<g, 256, 0, stream>>>(W, Wt, K, N, (unsigned long long)outz);
    };

    const unsigned short *qkvT_i[8], *woT_i[8], *fcT_i[8], *projT_i[8];
    const unsigned short* lmT = nullptr;
    unsigned short* sharedW = nullptr;

    if (bigPath) {
        unsigned short* qkvT = (unsigned short*)alloc(qkvT_n * 2);
        unsigned short* woT  = (unsigned short*)alloc(woT_n * 2);
        unsigned short* fcT  = (unsigned short*)alloc(fcT_n * 2);
        unsigned short* prT  = (unsigned short*)alloc(projT_n * 2);
        unsigned short* lmT2 = (unsigned short*)alloc(lmT_n * 2);
        wtr(Wq, qkvT,                          1024, 1024, 8, (size_t)1536 * 1024);
        wtr(Wk, qkvT + (size_t)1024 * 1024,    1024, 256,  8, (size_t)1536 * 1024);
        wtr(Wv, qkvT + (size_t)1280 * 1024,    1024, 256,  8, (size_t)1536 * 1024);
        wtr(Wo, woT,  1024, 1024, 8, (size_t)1024 * 1024);
        wtr(fcw, fcT, 1024, 4096, 8, (size_t)4096 * 1024);
        wtr(prw, prT, 4096, 1024, 8, (size_t)1024 * 4096);
        wtr(lmw, lmT2, 1024, 32000, 1, 0);
        for (int i = 0; i < 8; i++) {
            qkvT_i[i] = qkvT + (size_t)i * 1536 * 1024;
            woT_i[i]  = woT + (size_t)i * 1024 * 1024;
            fcT_i[i]  = fcT + (size_t)i * 4096 * 1024;
            projT_i[i] = prT + (size_t)i * 1024 * 4096;
        }
        lmT = lmT2;
    } else {
        // shared weight region, reused per layer; lm_head slot is the largest
        sharedW = (unsigned short*)alloc(lmT_n * 2);
        unsigned short* qkvT = sharedW;
        unsigned short* woT  = qkvT + (size_t)1536 * 1024;
        unsigned short* fcT  = woT + (size_t)1024 * 1024;
        unsigned short* prT  = fcT + (size_t)4096 * 1024;
        for (int i = 0; i < 8; i++) {
            qkvT_i[i] = qkvT; woT_i[i] = woT; fcT_i[i] = fcT; projT_i[i] = prT;
        }
        lmT = sharedW;
    }

    embed_kernel<<<1024, 256, 0, stream>>>(tok, wte, bigE, bscal, x);

    float* xin = x;   // residual stream in
    float* xalt = x2; // residual stream out of attention
    for (int i = 0; i < 8; i++) {
        if (!bigPath) {
            unsigned short* qkvT = (unsigned short*)qkvT_i[i];
            wtr(Wq + (size_t)i * 1048576, qkvT,                       1024, 1024, 1, 0);
            wtr(Wk + (size_t)i * 262144,  qkvT + (size_t)1024 * 1024, 1024, 256,  1, 0);
            wtr(Wv + (size_t)i * 262144,  qkvT + (size_t)1280 * 1024, 1024, 256,  1, 0);
            wtr(Wo + (size_t)i * 1048576, (unsigned short*)woT_i[i],  1024, 1024, 1, 0);
            wtr(fcw + (size_t)i * 4194304, (unsigned short*)fcT_i[i], 1024, 4096, 1, 0);
            wtr(prw + (size_t)i * 4194304, (unsigned short*)projT_i[i], 4096, 1024, 1, 0);
        }
        rmsnorm_kernel<<<1024, 256, 0, stream>>>(xin, xn);
        launch_gemm<0>(stream, xn, qkvT_i[i], nullptr, qkv, nullptr, 1024, 1536, 1024);
        gate_kernel<<<1024, 256, 0, stream>>>(xn, gw + (size_t)i * 16384, gb + i * 16, gbuf);
        qkrope_kernel<<<1024, 256, 0, stream>>>(qkv, qgain + i * 16, qb, kbuf);
        vmix_kernel<<<dim3(4, 16), 256, 0, stream>>>(qkv, v0, vt, vrl + 2 * i, i == 0 ? 1 : 0);
        attn_kernel<<<1024, 64, 0, stream>>>(qb, kbuf, vt, gbuf, ybuf);
        launch_gemm<1>(stream, ybuf, woT_i[i], xin, xalt, nullptr, 1024, 1024, 1024);
        rmsnorm_kernel<<<1024, 256, 0, stream>>>(xalt, xn);
        launch_gemm128<2>(stream, xn, fcT_i[i], nullptr, nullptr, hb, 1024, 4096, 1024);
        launch_gemm<1>(stream, hb, projT_i[i], xalt, xin, nullptr, 1024, 1024, 4096);
    }

    if (!bigPath) wtr(lmw, sharedW, 1024, 32000, 1, 0);
    rmsnorm_kernel<<<1024, 256, 0, stream>>>(xin, xn);
    launch_gemm128<0>(stream, xn, lmT, nullptr, out, nullptr, 1024, 32000, 1024);
}